// Round 12
// baseline (176.203 us; speedup 1.0000x reference)
//
#include <hip/hip_runtime.h>

typedef _Float16 f16x8 __attribute__((ext_vector_type(8)));
typedef _Float16 f16x4 __attribute__((ext_vector_type(4)));
typedef __fp16 h16x2 __attribute__((ext_vector_type(2)));  // cvt_pkrtz native type
typedef float f32x4 __attribute__((ext_vector_type(4)));

#define HH 2000
#define WW 1000
#define HWSZ (HH * WW)
#define NEG_INF (-3.0e38f)

// ---- monotone float<->uint encoding for atomicMax on floats ----
// fenc never returns 0, so buckets are initialized with plain memset(0).
__device__ __forceinline__ unsigned fenc(float f) {
    unsigned u = __float_as_uint(f);
    return (u & 0x80000000u) ? ~u : (u | 0x80000000u);
}
__device__ __forceinline__ float fdec(unsigned k) {
    unsigned u = (k & 0x80000000u) ? (k & 0x7fffffffu) : ~k;
    return __uint_as_float(u);
}

__global__ void decode_buckets(unsigned* __restrict__ buck, int n) {
    int i = blockIdx.x * blockDim.x + threadIdx.x;
    if (i < n) {
        unsigned k = buck[i];
        ((float*)buck)[i] = fdec(k);
    }
}

// MFMA 16x16x32 f16 layouts (gfx950, verified: absmax ~2e-3):
//   A: lane holds A[m=lane&15][k=(lane>>4)*8+j]
//   B: lane holds B[k=(lane>>4)*8+j][n=lane&15]
//   D: lane holds D[row=(lane>>4)*4+reg][col=lane&15]
//
// R25 = R24 (zero-LDS transitions + L4-as-MFMA, 63.4us) with 4 rows per
// iteration (4 independent dependency chains instead of 2). Rationale:
// MfmaUtil 16% + VALUBusy 34% -> ~50% of vector-issue idle; each wave
// exposes only 2 independent ~300cy chains and resident waves/SIMD (~2.2)
// have proven immovable (R17-R21). Chains/wave IS controllable: 4 rows/iter
// doubles latency-hiding ILP at identical per-row instruction count.
// Second row-pair uses a second SGPR base (rbase+2*WW) so all row offsets
// still fold into load instruction offsets.

__global__ __launch_bounds__(128) void mlp_max_mfma(
    const float* __restrict__ in,
    const float* __restrict__ w1, const float* __restrict__ b1,
    const float* __restrict__ w2, const float* __restrict__ b2,
    const float* __restrict__ w3, const float* __restrict__ b3,
    const float* __restrict__ w4, const float* __restrict__ b4,
    unsigned* __restrict__ rowbuck, unsigned* __restrict__ colbuck) {
    __shared__ float rowsm[2][16][16];   // [wave][row-in-block][px]

    const int tx = threadIdx.x;   // 0..63
    const int wv = threadIdx.y;   // 0..1 (independent waves)
    const int px = tx & 15;
    const int q = tx >> 4;        // lane group g

    // ---- weight A-fragments (persistent; k-maps as in R23/R24) ----
    f16x8 A1[2], A2[3], A3s0[3], A3s1[3], A4s0, A4s1;
    // L1: j0 -> ch q ; j1 -> ch 4+q ; j2 -> (q0: ch8, q1: bias); j>=3 zero.
#pragma unroll
    for (int t = 0; t < 2; ++t) {
        const int m = t * 16 + px;
#pragma unroll
        for (int j = 0; j < 8; ++j) {
            float v = 0.f;
            if (m < 18) {
                if (j == 0) v = w1[m * 9 + q];
                else if (j == 1) v = w1[m * 9 + 4 + q];
                else if (j == 2) {
                    if (q == 0) v = w1[m * 9 + 8];
                    else if (q == 1) v = b1[m];
                }
            }
            A1[t][j] = (_Float16)v;
        }
    }
    // L2: k=8q+j <-> ch 4q+j (j<4); q0: j4->ch16, j5->ch17, j6->bias.
#pragma unroll
    for (int t = 0; t < 3; ++t) {
        const int m = t * 16 + px;
#pragma unroll
        for (int j = 0; j < 8; ++j) {
            float v = 0.f;
            if (m < 36) {
                if (j < 4) v = w2[m * 18 + 4 * q + j];
                else if (q == 0) {
                    if (j == 4) v = w2[m * 18 + 16];
                    else if (j == 5) v = w2[m * 18 + 17];
                    else if (j == 6) v = b2[m];
                }
            }
            A2[t][j] = (_Float16)v;
        }
    }
    // L3 slice0: k=8q+j <-> ch 4q+j (j<4), ch 16+4q+(j-4) (j>=4).
    // L3 slice1: q0 j0-3 -> ch 32..35 ; q0 j4 -> bias ; else 0.
#pragma unroll
    for (int t = 0; t < 3; ++t) {
        const int m = t * 16 + px;
#pragma unroll
        for (int j = 0; j < 8; ++j) {
            float v = 0.f;
            if (m < 36) {
                const int ch = (j < 4) ? (4 * q + j) : (16 + 4 * q + (j - 4));
                v = w3[m * 36 + ch];
            }
            A3s0[t][j] = (_Float16)v;
            float v2 = 0.f;
            if (m < 36 && q == 0) {
                if (j < 4) v2 = w3[m * 36 + 32 + j];
                else if (j == 4) v2 = b3[m];
            }
            A3s1[t][j] = (_Float16)v2;
        }
    }
    // L4: same k-maps as L3 slices, but only row m=0 (px==0 lanes) nonzero.
#pragma unroll
    for (int j = 0; j < 8; ++j) {
        float v = 0.f, v2 = 0.f;
        if (px == 0) {
            const int ch = (j < 4) ? (4 * q + j) : (16 + 4 * q + (j - 4));
            v = w4[ch];
            if (q == 0) {
                if (j < 4) v2 = w4[32 + j];
                else if (j == 4) v2 = b4[0];
            }
        }
        A4s0[j] = (_Float16)v;
        A4s1[j] = (_Float16)v2;
    }

    const int col = blockIdx.x * 32 + wv * 16 + px;
    const int colc = (col < WW) ? col : (WW - 1);
    const bool colok = (col < WW);
    const int rb = blockIdx.y * 16;

    float colmax = NEG_INF;
    const f32x4 zf4 = {0.f, 0.f, 0.f, 0.f};
    const h16x2 z2 = {(__fp16)0.f, (__fp16)0.f};
    // loop-invariant bias-channel constants (g0 carries (1.0, 0))
    const h16x2 cB = (q == 0) ? __builtin_amdgcn_cvt_pkrtz(1.f, 0.f) : z2;

    union U8 { f16x8 v; h16x2 h[4]; };

    // ---- per-lane 32-bit element offsets for the k-permuted loads ----
    const int off0 = q * HWSZ + colc;        // ch q        (j=0)
    const int off1 = (4 + q) * HWSZ + colc;  // ch 4+q      (j=1)
    const int off2 = 8 * HWSZ + colc;        // ch 8 (q==0) (j=2)
    const float j2fill = (q == 1) ? 1.f : 0.f;  // bias / zero for j=2

    // ---- double-buffered raw input regs: [chain][j], 4 rows per buffer ----
    float bufA[4][3], bufB[4][3];

    auto LOAD = [&](int r, float (&v)[4][3]) {
        const float* rb0 = in + (size_t)r * WW;   // SGPR base rows 0,1
        const float* rb2 = rb0 + 2 * WW;          // SGPR base rows 2,3
#pragma unroll
        for (int h = 0; h < 2; ++h) {   // row within pair (offset h*WW folds)
            v[h][0] = rb0[off0 + h * WW];
            v[h][1] = rb0[off1 + h * WW];
            v[2 + h][0] = rb2[off0 + h * WW];
            v[2 + h][1] = rb2[off1 + h * WW];
            float x0 = j2fill, x2 = j2fill;
            if (q == 0) {
                x0 = rb0[off2 + h * WW];
                x2 = rb2[off2 + h * WW];
            }
            v[h][2] = x0;
            v[2 + h][2] = x2;
        }
    };

    // relu + pack helper
    auto maxpk = [&](float x, float y) {
        return __builtin_elementwise_max(__builtin_amdgcn_cvt_pkrtz(x, y), z2);
    };

    auto COMPUTE = [&](int it, const float (&v)[4][3]) {
        // ---- pack inputs to f16 (k-permuted layout; e4..e7 = 0) ----
        U8 bu[4];
#pragma unroll
        for (int c = 0; c < 4; ++c) {
            bu[c].h[0] = __builtin_amdgcn_cvt_pkrtz(v[c][0], v[c][1]);
            bu[c].h[1] = __builtin_amdgcn_cvt_pkrtz(v[c][2], 0.f);
            bu[c].h[2] = z2; bu[c].h[3] = z2;
        }

        // ---- layer 1 ----
        f32x4 D1[4][2];
#pragma unroll
        for (int c = 0; c < 4; ++c)
#pragma unroll
            for (int t = 0; t < 2; ++t)
                D1[c][t] = __builtin_amdgcn_mfma_f32_16x16x32_f16(A1[t], bu[c].v, zf4, 0, 0, 0);

        // ---- L1 epilogue -> B2 in registers ----
        U8 B2[4];
#pragma unroll
        for (int c = 0; c < 4; ++c) {
            B2[c].h[0] = maxpk(D1[c][0][0], D1[c][0][1]);
            B2[c].h[1] = maxpk(D1[c][0][2], D1[c][0][3]);
            B2[c].h[2] = maxpk(D1[c][1][0], D1[c][1][1]);
            B2[c].h[3] = cB;
        }

        // ---- layer 2 ----
        f32x4 D2[4][3];
#pragma unroll
        for (int c = 0; c < 4; ++c)
#pragma unroll
            for (int t = 0; t < 3; ++t)
                D2[c][t] = __builtin_amdgcn_mfma_f32_16x16x32_f16(A2[t], B2[c].v, zf4, 0, 0, 0);

        // ---- L2 epilogue -> B3 slices ----
        U8 B30[4], B31[4];
#pragma unroll
        for (int c = 0; c < 4; ++c) {
            B30[c].h[0] = maxpk(D2[c][0][0], D2[c][0][1]);
            B30[c].h[1] = maxpk(D2[c][0][2], D2[c][0][3]);
            B30[c].h[2] = maxpk(D2[c][1][0], D2[c][1][1]);
            B30[c].h[3] = maxpk(D2[c][1][2], D2[c][1][3]);
            B31[c].h[0] = maxpk(D2[c][2][0], D2[c][2][1]);
            B31[c].h[1] = maxpk(D2[c][2][2], D2[c][2][3]);
            B31[c].h[2] = cB;
            B31[c].h[3] = z2;
        }

        // ---- layer 3 (two K-slices) ----
        f32x4 D3[4][3];
#pragma unroll
        for (int c = 0; c < 4; ++c)
#pragma unroll
            for (int t = 0; t < 3; ++t) {
                D3[c][t] = __builtin_amdgcn_mfma_f32_16x16x32_f16(A3s0[t], B30[c].v, zf4, 0, 0, 0);
                D3[c][t] = __builtin_amdgcn_mfma_f32_16x16x32_f16(A3s1[t], B31[c].v, D3[c][t], 0, 0, 0);
            }

        // ---- L3 epilogue -> B4 slices ----
        U8 B40[4], B41[4];
#pragma unroll
        for (int c = 0; c < 4; ++c) {
            B40[c].h[0] = maxpk(D3[c][0][0], D3[c][0][1]);
            B40[c].h[1] = maxpk(D3[c][0][2], D3[c][0][3]);
            B40[c].h[2] = maxpk(D3[c][1][0], D3[c][1][1]);
            B40[c].h[3] = maxpk(D3[c][1][2], D3[c][1][3]);
            B41[c].h[0] = maxpk(D3[c][2][0], D3[c][2][1]);
            B41[c].h[1] = maxpk(D3[c][2][2], D3[c][2][3]);
            B41[c].h[2] = cB;
            B41[c].h[3] = z2;
        }

        // ---- layer 4 as MFMA: s(px)+b4 lands in lane (0,px) reg 0 ----
        f32x4 D4[4];
#pragma unroll
        for (int c = 0; c < 4; ++c) {
            D4[c] = __builtin_amdgcn_mfma_f32_16x16x32_f16(A4s0, B40[c].v, zf4, 0, 0, 0);
            D4[c] = __builtin_amdgcn_mfma_f32_16x16x32_f16(A4s1, B41[c].v, D4[c], 0, 0, 0);
        }

        colmax = fmaxf(colmax,
                       fmaxf(fmaxf(D4[0][0], D4[1][0]), fmaxf(D4[2][0], D4[3][0])));
        if (q == 0) {
            rowsm[wv][it * 4 + 0][px] = D4[0][0];
            rowsm[wv][it * 4 + 1][px] = D4[1][0];
            rowsm[wv][it * 4 + 2][px] = D4[2][0];
            rowsm[wv][it * 4 + 3][px] = D4[3][0];
        }
    };

    // ---- main loop: 4 iterations (16 rows), depth-1 ping-pong prefetch ----
    LOAD(rb, bufA);
#pragma unroll 1
    for (int it = 0; it < 4; it += 2) {
        LOAD(rb + (it + 1) * 4, bufB);   // prefetch odd half-step
        COMPUTE(it, bufA);
        if (it < 2) LOAD(rb + (it + 2) * 4, bufA);  // prefetch next even
        COMPUTE(it + 1, bufB);
    }

    // ---- end-of-wave flush (no barrier: rowsm slice is wave-private) ----
    if (q == 0 && colok) atomicMax(&colbuck[col], fenc(colmax));
    if (tx < 16) {
        const f32x4 v0 = *(const f32x4*)&rowsm[wv][tx][0];
        const f32x4 v1 = *(const f32x4*)&rowsm[wv][tx][4];
        const f32x4 v2 = *(const f32x4*)&rowsm[wv][tx][8];
        const f32x4 v3 = *(const f32x4*)&rowsm[wv][tx][12];
        float m = NEG_INF;
#pragma unroll
        for (int j = 0; j < 4; ++j) {
            m = fmaxf(m, fmaxf(fmaxf(v0[j], v1[j]), fmaxf(v2[j], v3[j])));
        }
        atomicMax(&rowbuck[rb + tx], fenc(m));
    }
}

extern "C" void kernel_launch(void* const* d_in, const int* in_sizes, int n_in,
                              void* d_out, int out_size, void* d_ws, size_t ws_size,
                              hipStream_t stream) {
    const float* in = (const float*)d_in[0];
    // d_in[1] = T_out (unused), d_in[2] = T_indices (identity, unused)
    const float* w1 = (const float*)d_in[3];
    const float* b1 = (const float*)d_in[4];
    const float* w2 = (const float*)d_in[5];
    const float* b2 = (const float*)d_in[6];
    const float* w3 = (const float*)d_in[7];
    const float* b3 = (const float*)d_in[8];
    const float* w4 = (const float*)d_in[9];
    const float* b4 = (const float*)d_in[10];

    unsigned* buck = (unsigned*)d_out;  // [0,2000) row maxes, [2000,3000) col maxes

    // fenc never produces 0, so memset-0 is a valid atomicMax identity.
    (void)hipMemsetAsync(buck, 0, 3000 * sizeof(unsigned), stream);

    dim3 block(64, 2);
    dim3 grid(32, 125);  // 32*32=1024 >= 1000 cols ; 125*16=2000 rows exactly
    mlp_max_mfma<<<grid, block, 0, stream>>>(in, w1, b1, w2, b2, w3, b3, w4, b4,
                                             buck, buck + 2000);

    decode_buckets<<<(3000 + 255) / 256, 256, 0, stream>>>(buck, 3000);
}

// Round 13
// 165.910 us; speedup vs baseline: 1.0620x; 1.0620x over previous
//
#include <hip/hip_runtime.h>

typedef _Float16 f16x8 __attribute__((ext_vector_type(8)));
typedef _Float16 f16x4 __attribute__((ext_vector_type(4)));
typedef __fp16 h16x2 __attribute__((ext_vector_type(2)));  // cvt_pkrtz native type
typedef float f32x4 __attribute__((ext_vector_type(4)));

#define HH 2000
#define WW 1000
#define HWSZ (HH * WW)
#define NEG_INF (-3.0e38f)

// ---- monotone float<->uint encoding for atomicMax on floats ----
// fenc never returns 0, so buckets are initialized with plain memset(0).
__device__ __forceinline__ unsigned fenc(float f) {
    unsigned u = __float_as_uint(f);
    return (u & 0x80000000u) ? ~u : (u | 0x80000000u);
}
__device__ __forceinline__ float fdec(unsigned k) {
    unsigned u = (k & 0x80000000u) ? (k & 0x7fffffffu) : ~k;
    return __uint_as_float(u);
}

__global__ void decode_buckets(unsigned* __restrict__ buck, int n) {
    int i = blockIdx.x * blockDim.x + threadIdx.x;
    if (i < n) {
        unsigned k = buck[i];
        ((float*)buck)[i] = fdec(k);
    }
}

// MFMA 16x16x32 f16 layouts (gfx950, verified: absmax ~2e-3):
//   A: lane holds A[m=lane&15][k=(lane>>4)*8+j]
//   B: lane holds B[k=(lane>>4)*8+j][n=lane&15]
//   D: lane holds D[row=(lane>>4)*4+reg][col=lane&15]
//
// R26 = R24 (best: 63.4us; zero-LDS transitions + L4-as-MFMA, 2 rows/iter)
// + depth-2 input prefetch. R17's depth-2 test was confounded: 16-float
// buffers cost +36 VGPR -> a wave of residency. Post-R22 a row-pair buffer
// is 6 floats; depth-2 costs +12 VGPR (68->~80), historically free
// (R16/R22 both ~28% occ at VGPR 68-80). Loads now issue 2 COMPUTE blocks
// (~600cy) ahead of use, covering the cold-HBM miss that depth-1 left
// exposed. R25's 4-chain ILP variant regressed (VGPR 100, occ 19%) and is
// reverted entirely.

__global__ __launch_bounds__(128) void mlp_max_mfma(
    const float* __restrict__ in,
    const float* __restrict__ w1, const float* __restrict__ b1,
    const float* __restrict__ w2, const float* __restrict__ b2,
    const float* __restrict__ w3, const float* __restrict__ b3,
    const float* __restrict__ w4, const float* __restrict__ b4,
    unsigned* __restrict__ rowbuck, unsigned* __restrict__ colbuck) {
    __shared__ float rowsm[2][16][16];   // [wave][row-in-block][px]

    const int tx = threadIdx.x;   // 0..63
    const int wv = threadIdx.y;   // 0..1 (independent waves)
    const int px = tx & 15;
    const int q = tx >> 4;        // lane group g

    // ---- weight A-fragments (persistent; k-maps as in R23/R24) ----
    f16x8 A1[2], A2[3], A3s0[3], A3s1[3], A4s0, A4s1;
    // L1: j0 -> ch q ; j1 -> ch 4+q ; j2 -> (q0: ch8, q1: bias); j>=3 zero.
#pragma unroll
    for (int t = 0; t < 2; ++t) {
        const int m = t * 16 + px;
#pragma unroll
        for (int j = 0; j < 8; ++j) {
            float v = 0.f;
            if (m < 18) {
                if (j == 0) v = w1[m * 9 + q];
                else if (j == 1) v = w1[m * 9 + 4 + q];
                else if (j == 2) {
                    if (q == 0) v = w1[m * 9 + 8];
                    else if (q == 1) v = b1[m];
                }
            }
            A1[t][j] = (_Float16)v;
        }
    }
    // L2: k=8q+j <-> ch 4q+j (j<4); q0: j4->ch16, j5->ch17, j6->bias.
#pragma unroll
    for (int t = 0; t < 3; ++t) {
        const int m = t * 16 + px;
#pragma unroll
        for (int j = 0; j < 8; ++j) {
            float v = 0.f;
            if (m < 36) {
                if (j < 4) v = w2[m * 18 + 4 * q + j];
                else if (q == 0) {
                    if (j == 4) v = w2[m * 18 + 16];
                    else if (j == 5) v = w2[m * 18 + 17];
                    else if (j == 6) v = b2[m];
                }
            }
            A2[t][j] = (_Float16)v;
        }
    }
    // L3 slice0: k=8q+j <-> ch 4q+j (j<4), ch 16+4q+(j-4) (j>=4).
    // L3 slice1: q0 j0-3 -> ch 32..35 ; q0 j4 -> bias ; else 0.
#pragma unroll
    for (int t = 0; t < 3; ++t) {
        const int m = t * 16 + px;
#pragma unroll
        for (int j = 0; j < 8; ++j) {
            float v = 0.f;
            if (m < 36) {
                const int ch = (j < 4) ? (4 * q + j) : (16 + 4 * q + (j - 4));
                v = w3[m * 36 + ch];
            }
            A3s0[t][j] = (_Float16)v;
            float v2 = 0.f;
            if (m < 36 && q == 0) {
                if (j < 4) v2 = w3[m * 36 + 32 + j];
                else if (j == 4) v2 = b3[m];
            }
            A3s1[t][j] = (_Float16)v2;
        }
    }
    // L4: same k-maps as L3 slices, but only row m=0 (px==0 lanes) nonzero.
#pragma unroll
    for (int j = 0; j < 8; ++j) {
        float v = 0.f, v2 = 0.f;
        if (px == 0) {
            const int ch = (j < 4) ? (4 * q + j) : (16 + 4 * q + (j - 4));
            v = w4[ch];
            if (q == 0) {
                if (j < 4) v2 = w4[32 + j];
                else if (j == 4) v2 = b4[0];
            }
        }
        A4s0[j] = (_Float16)v;
        A4s1[j] = (_Float16)v2;
    }

    const int col = blockIdx.x * 32 + wv * 16 + px;
    const int colc = (col < WW) ? col : (WW - 1);
    const bool colok = (col < WW);
    const int rb = blockIdx.y * 16;

    float colmax = NEG_INF;
    const f32x4 zf4 = {0.f, 0.f, 0.f, 0.f};
    const h16x2 z2 = {(__fp16)0.f, (__fp16)0.f};
    // loop-invariant bias-channel constants (g0 carries (1.0, 0))
    const h16x2 cB = (q == 0) ? __builtin_amdgcn_cvt_pkrtz(1.f, 0.f) : z2;

    union U8 { f16x8 v; h16x2 h[4]; };

    // ---- per-lane 32-bit element offsets for the k-permuted loads ----
    const int off0 = q * HWSZ + colc;        // ch q        (j=0)
    const int off1 = (4 + q) * HWSZ + colc;  // ch 4+q      (j=1)
    const int off2 = 8 * HWSZ + colc;        // ch 8 (q==0) (j=2)
    const float j2fill = (q == 1) ? 1.f : 0.f;  // bias / zero for j=2

    // ---- quad-buffered raw input regs (depth-2 prefetch), 6 floats each ----
    float c0a[3], c0b[3], c1a[3], c1b[3], c2a[3], c2b[3], c3a[3], c3b[3];

    auto LOAD = [&](int r, float (&v0)[3], float (&v1)[3]) {
        const float* rbase = in + (size_t)r * WW;   // wave-uniform base
        v0[0] = rbase[off0]; v1[0] = rbase[off0 + WW];
        v0[1] = rbase[off1]; v1[1] = rbase[off1 + WW];
        float x0 = j2fill, x1 = j2fill;
        if (q == 0) { x0 = rbase[off2]; x1 = rbase[off2 + WW]; }
        v0[2] = x0; v1[2] = x1;
    };

    // relu + pack helper
    auto maxpk = [&](float x, float y) {
        return __builtin_elementwise_max(__builtin_amdgcn_cvt_pkrtz(x, y), z2);
    };

    auto COMPUTE = [&](int it, const float (&v0)[3], const float (&v1)[3]) {
        // ---- pack inputs to f16 (k-permuted layout; e4..e7 = 0) ----
        U8 b0u, b1u;
        b0u.h[0] = __builtin_amdgcn_cvt_pkrtz(v0[0], v0[1]);
        b0u.h[1] = __builtin_amdgcn_cvt_pkrtz(v0[2], 0.f);
        b0u.h[2] = z2; b0u.h[3] = z2;
        b1u.h[0] = __builtin_amdgcn_cvt_pkrtz(v1[0], v1[1]);
        b1u.h[1] = __builtin_amdgcn_cvt_pkrtz(v1[2], 0.f);
        b1u.h[2] = z2; b1u.h[3] = z2;

        // ---- layer 1 ----
        f32x4 D1a[2], D1b[2];
#pragma unroll
        for (int t = 0; t < 2; ++t) {
            D1a[t] = __builtin_amdgcn_mfma_f32_16x16x32_f16(A1[t], b0u.v, zf4, 0, 0, 0);
            D1b[t] = __builtin_amdgcn_mfma_f32_16x16x32_f16(A1[t], b1u.v, zf4, 0, 0, 0);
        }

        // ---- L1 epilogue -> B2 in registers (zero data movement) ----
        U8 B2a, B2b;
        B2a.h[0] = maxpk(D1a[0][0], D1a[0][1]);
        B2a.h[1] = maxpk(D1a[0][2], D1a[0][3]);
        B2a.h[2] = maxpk(D1a[1][0], D1a[1][1]);
        B2a.h[3] = cB;
        B2b.h[0] = maxpk(D1b[0][0], D1b[0][1]);
        B2b.h[1] = maxpk(D1b[0][2], D1b[0][3]);
        B2b.h[2] = maxpk(D1b[1][0], D1b[1][1]);
        B2b.h[3] = cB;

        // ---- layer 2 ----
        f32x4 D2a[3], D2b[3];
#pragma unroll
        for (int t = 0; t < 3; ++t) {
            D2a[t] = __builtin_amdgcn_mfma_f32_16x16x32_f16(A2[t], B2a.v, zf4, 0, 0, 0);
            D2b[t] = __builtin_amdgcn_mfma_f32_16x16x32_f16(A2[t], B2b.v, zf4, 0, 0, 0);
        }

        // ---- L2 epilogue -> B3 slices in registers ----
        U8 B3a0, B3b0, B3a1, B3b1;
        B3a0.h[0] = maxpk(D2a[0][0], D2a[0][1]);
        B3a0.h[1] = maxpk(D2a[0][2], D2a[0][3]);
        B3a0.h[2] = maxpk(D2a[1][0], D2a[1][1]);
        B3a0.h[3] = maxpk(D2a[1][2], D2a[1][3]);
        B3a1.h[0] = maxpk(D2a[2][0], D2a[2][1]);
        B3a1.h[1] = maxpk(D2a[2][2], D2a[2][3]);
        B3a1.h[2] = cB;
        B3a1.h[3] = z2;
        B3b0.h[0] = maxpk(D2b[0][0], D2b[0][1]);
        B3b0.h[1] = maxpk(D2b[0][2], D2b[0][3]);
        B3b0.h[2] = maxpk(D2b[1][0], D2b[1][1]);
        B3b0.h[3] = maxpk(D2b[1][2], D2b[1][3]);
        B3b1.h[0] = maxpk(D2b[2][0], D2b[2][1]);
        B3b1.h[1] = maxpk(D2b[2][2], D2b[2][3]);
        B3b1.h[2] = cB;
        B3b1.h[3] = z2;

        // ---- layer 3 (two K-slices) ----
        f32x4 D3a[3], D3b[3];
#pragma unroll
        for (int t = 0; t < 3; ++t) {
            D3a[t] = __builtin_amdgcn_mfma_f32_16x16x32_f16(A3s0[t], B3a0.v, zf4, 0, 0, 0);
            D3a[t] = __builtin_amdgcn_mfma_f32_16x16x32_f16(A3s1[t], B3a1.v, D3a[t], 0, 0, 0);
            D3b[t] = __builtin_amdgcn_mfma_f32_16x16x32_f16(A3s0[t], B3b0.v, zf4, 0, 0, 0);
            D3b[t] = __builtin_amdgcn_mfma_f32_16x16x32_f16(A3s1[t], B3b1.v, D3b[t], 0, 0, 0);
        }

        // ---- L3 epilogue -> B4 slices (same pattern as B3) ----
        U8 B4a0, B4b0, B4a1, B4b1;
        B4a0.h[0] = maxpk(D3a[0][0], D3a[0][1]);
        B4a0.h[1] = maxpk(D3a[0][2], D3a[0][3]);
        B4a0.h[2] = maxpk(D3a[1][0], D3a[1][1]);
        B4a0.h[3] = maxpk(D3a[1][2], D3a[1][3]);
        B4a1.h[0] = maxpk(D3a[2][0], D3a[2][1]);
        B4a1.h[1] = maxpk(D3a[2][2], D3a[2][3]);
        B4a1.h[2] = cB;
        B4a1.h[3] = z2;
        B4b0.h[0] = maxpk(D3b[0][0], D3b[0][1]);
        B4b0.h[1] = maxpk(D3b[0][2], D3b[0][3]);
        B4b0.h[2] = maxpk(D3b[1][0], D3b[1][1]);
        B4b0.h[3] = maxpk(D3b[1][2], D3b[1][3]);
        B4b1.h[0] = maxpk(D3b[2][0], D3b[2][1]);
        B4b1.h[1] = maxpk(D3b[2][2], D3b[2][3]);
        B4b1.h[2] = cB;
        B4b1.h[3] = z2;

        // ---- layer 4 as MFMA: s(px)+b4 lands in lane (0,px) reg 0 ----
        f32x4 D4a = __builtin_amdgcn_mfma_f32_16x16x32_f16(A4s0, B4a0.v, zf4, 0, 0, 0);
        D4a = __builtin_amdgcn_mfma_f32_16x16x32_f16(A4s1, B4a1.v, D4a, 0, 0, 0);
        f32x4 D4b = __builtin_amdgcn_mfma_f32_16x16x32_f16(A4s0, B4b0.v, zf4, 0, 0, 0);
        D4b = __builtin_amdgcn_mfma_f32_16x16x32_f16(A4s1, B4b1.v, D4b, 0, 0, 0);

        const float sa = D4a[0];
        const float sb = D4b[0];
        colmax = fmaxf(colmax, fmaxf(sa, sb));
        if (q == 0) {
            rowsm[wv][it * 2][px] = sa;
            rowsm[wv][it * 2 + 1][px] = sb;
        }
    };

    // ---- main loop: 8 iterations (16 rows), depth-2 prefetch, unroll 4 ----
    LOAD(rb + 0, c0a, c0b);
    LOAD(rb + 2, c1a, c1b);
#pragma unroll 1
    for (int it = 0; it < 8; it += 4) {
        LOAD(rb + (it + 2) * 2, c2a, c2b);
        COMPUTE(it, c0a, c0b);
        LOAD(rb + (it + 3) * 2, c3a, c3b);
        COMPUTE(it + 1, c1a, c1b);
        if (it == 0) LOAD(rb + (it + 4) * 2, c0a, c0b);
        COMPUTE(it + 2, c2a, c2b);
        if (it == 0) LOAD(rb + (it + 5) * 2, c1a, c1b);
        COMPUTE(it + 3, c3a, c3b);
    }

    // ---- end-of-wave flush (no barrier: rowsm slice is wave-private) ----
    if (q == 0 && colok) atomicMax(&colbuck[col], fenc(colmax));
    if (tx < 16) {
        const f32x4 v0 = *(const f32x4*)&rowsm[wv][tx][0];
        const f32x4 v1 = *(const f32x4*)&rowsm[wv][tx][4];
        const f32x4 v2 = *(const f32x4*)&rowsm[wv][tx][8];
        const f32x4 v3 = *(const f32x4*)&rowsm[wv][tx][12];
        float m = NEG_INF;
#pragma unroll
        for (int j = 0; j < 4; ++j) {
            m = fmaxf(m, fmaxf(fmaxf(v0[j], v1[j]), fmaxf(v2[j], v3[j])));
        }
        atomicMax(&rowbuck[rb + tx], fenc(m));
    }
}

extern "C" void kernel_launch(void* const* d_in, const int* in_sizes, int n_in,
                              void* d_out, int out_size, void* d_ws, size_t ws_size,
                              hipStream_t stream) {
    const float* in = (const float*)d_in[0];
    // d_in[1] = T_out (unused), d_in[2] = T_indices (identity, unused)
    const float* w1 = (const float*)d_in[3];
    const float* b1 = (const float*)d_in[4];
    const float* w2 = (const float*)d_in[5];
    const float* b2 = (const float*)d_in[6];
    const float* w3 = (const float*)d_in[7];
    const float* b3 = (const float*)d_in[8];
    const float* w4 = (const float*)d_in[9];
    const float* b4 = (const float*)d_in[10];

    unsigned* buck = (unsigned*)d_out;  // [0,2000) row maxes, [2000,3000) col maxes

    // fenc never produces 0, so memset-0 is a valid atomicMax identity.
    (void)hipMemsetAsync(buck, 0, 3000 * sizeof(unsigned), stream);

    dim3 block(64, 2);
    dim3 grid(32, 125);  // 32*32=1024 >= 1000 cols ; 125*16=2000 rows exactly
    mlp_max_mfma<<<grid, block, 0, stream>>>(in, w1, b1, w2, b2, w3, b3, w4, b4,
                                             buck, buck + 2000);

    decode_buckets<<<(3000 + 255) / 256, 256, 0, stream>>>(buck, 3000);
}